// Round 3
// baseline (304.483 us; speedup 1.0000x reference)
//
#include <hip/hip_runtime.h>
#include <stdint.h>

typedef __attribute__((ext_vector_type(8))) short short8;
typedef __attribute__((ext_vector_type(4))) float floatx4;

#define AS1 __attribute__((address_space(1)))
#define AS3 __attribute__((address_space(3)))

__device__ __forceinline__ void gld16(const void* g, void* l) {
  __builtin_amdgcn_global_load_lds((AS1 const void*)g, (AS3 void*)l, 16, 0, 0);
}

__device__ __forceinline__ unsigned short f2bf(float f) {
  unsigned int u = __float_as_uint(f);
  return (unsigned short)((u + 0x7fffu + ((u >> 16) & 1u)) >> 16);
}

// ---------------------------------------------------------------------------
// prep: weights to N-major bf16; fold t*w0[576] into bias0.
// ---------------------------------------------------------------------------
__global__ __launch_bounds__(256) void k_prep(
    const float* __restrict__ w0, const float* __restrict__ b0,
    const float* __restrict__ w1, const float* __restrict__ w2,
    const float* __restrict__ w3, const float* __restrict__ w4,
    const float* __restrict__ coord,
    unsigned short* __restrict__ wT0, unsigned short* __restrict__ wT1,
    unsigned short* __restrict__ wT2, unsigned short* __restrict__ wT3,
    unsigned short* __restrict__ wT4, float* __restrict__ b0p) {
  int e = blockIdx.x * 256 + threadIdx.x;
  if (e < 147456) {
    int n = e / 576, kp = e - n * 576;
    int tap = kp >> 6, c = kp & 63;
    wT0[e] = f2bf(w0[(c * 9 + tap) * 256 + n]);
  } else if (e < 147456 + 3 * 65536) {
    int e2 = e - 147456;
    int l = e2 >> 16;
    int r = e2 & 65535;
    int n = r >> 8, k = r & 255;
    const float* w = (l == 0) ? w1 : (l == 1) ? w2 : w3;
    unsigned short* wt = (l == 0) ? wT1 : (l == 1) ? wT2 : wT3;
    wt[r] = f2bf(w[k * 256 + n]);
  } else if (e < 147456 + 3 * 65536 + 8192) {
    int r = e - (147456 + 3 * 65536);
    int n = r >> 8, k = r & 255;
    wT4[r] = (n < 27) ? f2bf(w4[k * 27 + n]) : (unsigned short)0;
  } else if (e < 147456 + 3 * 65536 + 8192 + 256) {
    int n = e - (147456 + 3 * 65536 + 8192);
    b0p[n] = b0[n] + coord[2] * w0[576 * 256 + n];
  }
}

// ---------------------------------------------------------------------------
// featT: X0[p][c] = bf16(feat[b][c][y][x]), p = b*65536 + y*256 + x. Row=128B.
// ---------------------------------------------------------------------------
__global__ __launch_bounds__(256) void k_featT(const float* __restrict__ feat,
                                               unsigned short* __restrict__ X0) {
  const int p = blockIdx.x * 256 + threadIdx.x;
  const int b = p >> 16;
  const int off = p & 65535;
  const float* src = feat + ((int64_t)b << 22) + off;
  unsigned int tw[32];
#pragma unroll
  for (int c = 0; c < 32; ++c) {
    float lo = src[(int64_t)(2 * c) << 16];
    float hi = src[(int64_t)(2 * c + 1) << 16];
    tw[c] = (unsigned int)f2bf(lo) | ((unsigned int)f2bf(hi) << 16);
  }
  uint4* dst = (uint4*)(X0 + (int64_t)p * 64);
#pragma unroll
  for (int k = 0; k < 8; ++k) {
    uint4 v;
    v.x = tw[4 * k]; v.y = tw[4 * k + 1]; v.z = tw[4 * k + 2]; v.w = tw[4 * k + 3];
    dst[k] = v;
  }
}

// ---------------------------------------------------------------------------
// Fused MLP, single 32KB in-place H buffer.
// Block = 64 pixels, 4 waves. A = weights (M=features, global/L2, software-
// pipelined 1 K-step ahead), B = activations (N=64 px, LDS). mid_K reads ALL
// of H; barrier; epilogue writes H in place (per-wave-disjoint chunks).
// H layout: px-major 512B/px, chunk c at px*512 + ((c^(px&7))<<4).
// ---------------------------------------------------------------------------
__device__ __forceinline__ void mid_K(floatx4 (&acc)[4][4], const char* H,
                                      const unsigned short* WT,
                                      int wv, int lm, int q) {
  const char* a0 = (const char*)WT + (wv * 64 + lm) * 512 + q * 16;
  const int l7 = lm & 7;
  short8 af[4];
#pragma unroll
  for (int i = 0; i < 4; ++i) af[i] = *(const short8*)(a0 + i * 8192);
#pragma unroll
  for (int kk = 0; kk < 8; ++kk) {
    short8 afn[4];
    if (kk < 7) {
#pragma unroll
      for (int i = 0; i < 4; ++i)
        afn[i] = *(const short8*)(a0 + i * 8192 + (kk + 1) * 64);
    }
    short8 bfr[4];
#pragma unroll
    for (int j = 0; j < 4; ++j) {
      const int pp = j * 16 + lm;
      const int c = kk * 4 + q;
      bfr[j] = *(const short8*)(H + pp * 512 + ((c ^ l7) << 4));
    }
#pragma unroll
    for (int i = 0; i < 4; ++i)
#pragma unroll
      for (int j = 0; j < 4; ++j)
        acc[i][j] = __builtin_amdgcn_mfma_f32_16x16x32_bf16(af[i], bfr[j], acc[i][j], 0, 0, 0);
    if (kk < 7) {
#pragma unroll
      for (int i = 0; i < 4; ++i) af[i] = afn[i];
    }
  }
}

__device__ __forceinline__ void epilogue(floatx4 (&acc)[4][4],
                                         const float* __restrict__ bias,
                                         char* Hout, int wv, int lm, int q) {
  const int l7 = lm & 7;
#pragma unroll
  for (int i = 0; i < 4; ++i) {
    const float4 bv = *(const float4*)(bias + wv * 64 + i * 16 + q * 4);
#pragma unroll
    for (int j = 0; j < 4; ++j) {
      unsigned int lo = (unsigned int)f2bf(__sinf(30.0f * (acc[i][j][0] + bv.x)))
                      | ((unsigned int)f2bf(__sinf(30.0f * (acc[i][j][1] + bv.y))) << 16);
      unsigned int hi = (unsigned int)f2bf(__sinf(30.0f * (acc[i][j][2] + bv.z)))
                      | ((unsigned int)f2bf(__sinf(30.0f * (acc[i][j][3] + bv.w))) << 16);
      const int pp = j * 16 + lm;
      const int c = wv * 8 + i * 2 + (q >> 1);
      uint2* dst = (uint2*)(Hout + pp * 512 + ((c ^ l7) << 4) + (q & 1) * 8);
      uint2 v; v.x = lo; v.y = hi;
      *dst = v;
    }
  }
}

__global__ __launch_bounds__(256, 4) void k_fused(
    const unsigned short* __restrict__ X0,
    const unsigned short* __restrict__ wT0, const float* __restrict__ b0p,
    const unsigned short* __restrict__ wT1, const float* __restrict__ b1,
    const unsigned short* __restrict__ wT2, const float* __restrict__ b2,
    const unsigned short* __restrict__ wT3, const float* __restrict__ b3,
    const unsigned short* __restrict__ wT4, const float* __restrict__ b4,
    float* __restrict__ pat) {
  __shared__ alignas(128) char H[32768];
  const int tid = threadIdx.x;
  const int bid = blockIdx.x;
  const int pbase = bid * 64;
  const int bimg = pbase >> 16;
  const int y = (pbase >> 8) & 255;
  const int x0 = pbase & 255;  // 0,64,128,192
  const int lm = tid & 15;
  const int q = (tid & 63) >> 4;
  const int wv = tid >> 6;
  const int l7 = lm & 7;

  // ---- stage 3x66 pixel patch (1584 chunks of 16B, swizzled by row&7) ----
#pragma unroll
  for (int iter = 0; iter < 7; ++iter) {
    const int ci = iter * 256 + tid;
    if (ci < 1584) {
      const int rp = ci >> 3;
      const int row = rp / 66;
      const int col = rp - row * 66;
      int gy = y + row - 1;
      int gx = x0 + col - 1;
      gy = gy < 0 ? 0 : (gy > 255 ? 255 : gy);
      gx = gx < 0 ? 0 : (gx > 255 ? 255 : gx);
      const int gch = (ci & 7) ^ (rp & 7);
      const int p = (bimg << 16) + (gy << 8) + gx;
      gld16((const char*)X0 + (int64_t)p * 128 + gch * 16, H + ci * 16);
    }
  }
  __syncthreads();
  // zero out-of-range pixels (image edges)
#pragma unroll
  for (int iter = 0; iter < 7; ++iter) {
    const int ci = iter * 256 + tid;
    if (ci < 1584) {
      const int rp = ci >> 3;
      const int row = rp / 66;
      const int col = rp - row * 66;
      const int gy = y + row - 1;
      const int gx = x0 + col - 1;
      if ((unsigned)gy >= 256u || (unsigned)gx >= 256u) {
        uint4 z; z.x = 0; z.y = 0; z.z = 0; z.w = 0;
        *(uint4*)(H + ci * 16) = z;
      }
    }
  }
  __syncthreads();

  floatx4 zero = {0.0f, 0.0f, 0.0f, 0.0f};
  floatx4 acc[4][4];
#pragma unroll
  for (int i = 0; i < 4; ++i)
#pragma unroll
    for (int j = 0; j < 4; ++j) acc[i][j] = zero;

  // ---- layer 0: implicit 3x3 conv, 18 (tap,kk) steps, af pipelined ----
  {
    const char* a0 = (const char*)wT0 + (wv * 64 + lm) * 1152 + q * 16;
    short8 af[4];
#pragma unroll
    for (int i = 0; i < 4; ++i) af[i] = *(const short8*)(a0 + i * 18432);
#pragma unroll
    for (int t = 0; t < 18; ++t) {
      const int tap = t >> 1;
      const int kk = t & 1;
      short8 afn[4];
      if (t < 17) {
        const int tn = t + 1;
        const int tapn = tn >> 1;
        const int kkn = tn & 1;
#pragma unroll
        for (int i = 0; i < 4; ++i)
          afn[i] = *(const short8*)(a0 + i * 18432 + tapn * 128 + kkn * 64);
      }
      const int dyr = tap / 3;
      const int dxr = tap - dyr * 3;
      const int rpb = dyr * 66 + dxr;
      short8 bfr[4];
#pragma unroll
      for (int j = 0; j < 4; ++j) {
        const int rp = rpb + j * 16 + lm;
        const int c = kk * 4 + q;
        bfr[j] = *(const short8*)(H + rp * 128 + ((c ^ (rp & 7)) << 4));
      }
#pragma unroll
      for (int i = 0; i < 4; ++i)
#pragma unroll
        for (int j = 0; j < 4; ++j)
          acc[i][j] = __builtin_amdgcn_mfma_f32_16x16x32_bf16(af[i], bfr[j], acc[i][j], 0, 0, 0);
      if (t < 17) {
#pragma unroll
        for (int i = 0; i < 4; ++i) af[i] = afn[i];
      }
    }
  }
  __syncthreads();             // all waves done reading patch
  epilogue(acc, b0p, H, wv, lm, q);
  __syncthreads();

  // ---- layers 1..3: in-place H ----
  const unsigned short* WTs[3] = {wT1, wT2, wT3};
  const float* Bs[3] = {b1, b2, b3};
#pragma unroll 1
  for (int l = 0; l < 3; ++l) {
#pragma unroll
    for (int i = 0; i < 4; ++i)
#pragma unroll
      for (int j = 0; j < 4; ++j) acc[i][j] = zero;
    mid_K(acc, H, WTs[l], wv, lm, q);
    __syncthreads();           // all reads of H done
    epilogue(acc, Bs[l], H, wv, lm, q);
    __syncthreads();
  }

  // ---- layer 4: H -> pat (each wave: 16-px strip x 32 features) ----
  {
    floatx4 a4[2];
    a4[0] = zero; a4[1] = zero;
    const char* aw = (const char*)wT4 + lm * 512 + q * 16;
    const int pp4 = wv * 16 + lm;
#pragma unroll
    for (int kk = 0; kk < 8; ++kk) {
      const int c = kk * 4 + q;
      short8 bfr = *(const short8*)(H + pp4 * 512 + ((c ^ l7) << 4));
#pragma unroll
      for (int i = 0; i < 2; ++i) {
        short8 af = *(const short8*)(aw + i * 8192 + kk * 64);
        a4[i] = __builtin_amdgcn_mfma_f32_16x16x32_bf16(af, bfr, a4[i], 0, 0, 0);
      }
    }
    float* outp = pat + (int64_t)(pbase + pp4) * 32;
#pragma unroll
    for (int i = 0; i < 2; ++i)
#pragma unroll
      for (int r = 0; r < 4; ++r) {
        const int g = i * 16 + q * 4 + r;
        if (g < 27) outp[g] = a4[i][r] + b4[g];
      }
  }
}

// fold3: out[b][c][y][x] = sum_{i,j} pat[(b,y+1-i,x+1-j)][c*9+i*3+j]
__global__ __launch_bounds__(256) void k_fold(const float* __restrict__ pat,
                                              float* __restrict__ out) {
  const int e = blockIdx.x * 256 + threadIdx.x;  // < 393216
  const int x = e & 255;
  const int y = (e >> 8) & 255;
  const int bc = e >> 16;
  const int c = bc % 3;
  const int b = bc / 3;
  float s = 0.0f;
#pragma unroll
  for (int i = 0; i < 3; ++i) {
    const int yy = y + 1 - i;
    if (yy < 0 || yy > 255) continue;
#pragma unroll
    for (int j = 0; j < 3; ++j) {
      const int xx = x + 1 - j;
      if (xx < 0 || xx > 255) continue;
      s += pat[(int64_t)((b << 16) + yy * 256 + xx) * 32 + c * 9 + i * 3 + j];
    }
  }
  out[e] = s;
}

extern "C" void kernel_launch(void* const* d_in, const int* in_sizes, int n_in,
                              void* d_out, int out_size, void* d_ws, size_t ws_size,
                              hipStream_t stream) {
  const float* feat  = (const float*)d_in[0];
  const float* coord = (const float*)d_in[1];
  const float* w0 = (const float*)d_in[2];
  const float* b0 = (const float*)d_in[3];
  const float* w1 = (const float*)d_in[4];
  const float* b1 = (const float*)d_in[5];
  const float* w2 = (const float*)d_in[6];
  const float* b2 = (const float*)d_in[7];
  const float* w3 = (const float*)d_in[8];
  const float* b3 = (const float*)d_in[9];
  const float* w4 = (const float*)d_in[10];
  const float* b4 = (const float*)d_in[11];

  char* ws = (char*)d_ws;
  unsigned short* X0  = (unsigned short*)(ws);                 // 16.78 MB
  float*          pat = (float*)(ws + 16777216);               // 16.78 MB
  unsigned short* wT0 = (unsigned short*)(ws + 33554432);      // 294912 B
  unsigned short* wT1 = (unsigned short*)(ws + 33849344);      // 131072 B
  unsigned short* wT2 = (unsigned short*)(ws + 33980416);
  unsigned short* wT3 = (unsigned short*)(ws + 34111488);
  unsigned short* wT4 = (unsigned short*)(ws + 34242560);      // 16384 B
  float*          b0p = (float*)(ws + 34258944);               // 1024 B
  float* out = (float*)d_out;

  hipLaunchKernelGGL(k_prep, dim3(1377), dim3(256), 0, stream,
                     w0, b0, w1, w2, w3, w4, coord, wT0, wT1, wT2, wT3, wT4, b0p);
  hipLaunchKernelGGL(k_featT, dim3(512), dim3(256), 0, stream, feat, X0);
  hipLaunchKernelGGL(k_fused, dim3(2048), dim3(256), 0, stream,
                     X0, wT0, b0p, wT1, b1, wT2, b2, wT3, b3, wT4, b4, pat);
  hipLaunchKernelGGL(k_fold, dim3(1536), dim3(256), 0, stream, pat, out);
}

// Round 4
// 248.314 us; speedup vs baseline: 1.2262x; 1.2262x over previous
//
#include <hip/hip_runtime.h>
#include <stdint.h>

typedef __attribute__((ext_vector_type(8))) short short8;
typedef __attribute__((ext_vector_type(4))) float floatx4;

#define AS1 __attribute__((address_space(1)))
#define AS3 __attribute__((address_space(3)))

__device__ __forceinline__ void gld16(const void* g, void* l) {
  __builtin_amdgcn_global_load_lds((AS1 const void*)g, (AS3 void*)l, 16, 0, 0);
}

__device__ __forceinline__ unsigned short f2bf(float f) {
  unsigned int u = __float_as_uint(f);
  return (unsigned short)((u + 0x7fffu + ((u >> 16) & 1u)) >> 16);
}

// ---------------------------------------------------------------------------
// k_pre: blocks [0,512) = featT (X0[p][c] = bf16 feat, pixel-major 128B rows);
// blocks [512,...) = weight packing into MFMA A-fragment order.
// Packed layout: per (panel of 16 out-features, kk) one 1KB chunk, element
// (lane,j) at chunk + lane*16 + j*2  ->  feature = panel*16 + (lane&15),
// k = kk*32 + (lane>>4)*8 + j. Every af load is a coalesced 1KB burst.
// wp0: 16 panels x 9 taps x 2 kk (c = kk*32+..., per tap)      294912 B
// wp{1,2,3}: 16 panels x 8 kk                                  131072 B each
// wp4: 2 panels x 8 kk (feature>=27 -> 0)                       16384 B
// b0p[n] = b0[n] + t*w0[576*256+n];  b4p = b4 padded to 32.
// ---------------------------------------------------------------------------
__global__ __launch_bounds__(256) void k_pre(
    const float* __restrict__ feat,
    const float* __restrict__ w0, const float* __restrict__ b0,
    const float* __restrict__ w1, const float* __restrict__ w2,
    const float* __restrict__ w3, const float* __restrict__ w4,
    const float* __restrict__ b4, const float* __restrict__ coord,
    unsigned short* __restrict__ X0,
    unsigned short* __restrict__ wp0, unsigned short* __restrict__ wp1,
    unsigned short* __restrict__ wp2, unsigned short* __restrict__ wp3,
    unsigned short* __restrict__ wp4, float* __restrict__ b0p,
    float* __restrict__ b4p) {
  const int bid = blockIdx.x;
  const int tid = threadIdx.x;
  if (bid < 512) {
    const int p = bid * 256 + tid;
    const int b = p >> 16;
    const int off = p & 65535;
    const float* src = feat + ((int64_t)b << 22) + off;
    unsigned int tw[32];
#pragma unroll
    for (int c = 0; c < 32; ++c) {
      float lo = src[(int64_t)(2 * c) << 16];
      float hi = src[(int64_t)(2 * c + 1) << 16];
      tw[c] = (unsigned int)f2bf(lo) | ((unsigned int)f2bf(hi) << 16);
    }
    uint4* dst = (uint4*)(X0 + (int64_t)p * 64);
#pragma unroll
    for (int k = 0; k < 8; ++k) {
      uint4 v;
      v.x = tw[4 * k]; v.y = tw[4 * k + 1]; v.z = tw[4 * k + 2]; v.w = tw[4 * k + 3];
      dst[k] = v;
    }
    return;
  }
  const int e = (bid - 512) * 256 + tid;
  if (e < 147456) {
    // wp0
    const int j = e & 7, lane = (e >> 3) & 63, r = e >> 9;
    const int kk = r & 1, s = r >> 1;
    const int tap = s % 9, panel = s / 9;
    const int feature = panel * 16 + (lane & 15);
    const int c = kk * 32 + (lane >> 4) * 8 + j;
    wp0[e] = f2bf(w0[(c * 9 + tap) * 256 + feature]);
  } else if (e < 344064) {
    const int e2 = e - 147456;
    const int l = e2 >> 16;
    const int u = e2 & 65535;
    const int j = u & 7, lane = (u >> 3) & 63, kk = (u >> 9) & 7, panel = (u >> 12) & 15;
    const int feature = panel * 16 + (lane & 15);
    const int k = kk * 32 + (lane >> 4) * 8 + j;
    const float* w = (l == 0) ? w1 : (l == 1) ? w2 : w3;
    unsigned short* wt = (l == 0) ? wp1 : (l == 1) ? wp2 : wp3;
    wt[u] = f2bf(w[k * 256 + feature]);
  } else if (e < 352256) {
    const int u = e - 344064;
    const int j = u & 7, lane = (u >> 3) & 63, kk = (u >> 9) & 7, i = (u >> 12) & 1;
    const int feature = i * 16 + (lane & 15);
    const int k = kk * 32 + (lane >> 4) * 8 + j;
    wp4[u] = (feature < 27) ? f2bf(w4[k * 27 + feature]) : (unsigned short)0;
  } else if (e < 352512) {
    const int n = e - 352256;
    b0p[n] = b0[n] + coord[2] * w0[576 * 256 + n];
  } else if (e < 352544) {
    const int n = e - 352512;
    b4p[n] = (n < 27) ? b4[n] : 0.0f;
  }
}

// ---------------------------------------------------------------------------
// Fused MLP, single 32KB in-place H buffer, packed coalesced weight loads.
// Block = 64 pixels, 4 waves. A = weights (1KB lane-linear bursts, L2-hot,
// pipelined 1 step ahead), B = activations (LDS). mid_K reads ALL of H;
// barrier; epilogue writes H in place.
// H layout: px-major 512B/px, chunk c at px*512 + ((c^(px&7))<<4).
// ---------------------------------------------------------------------------
__device__ __forceinline__ void mid_K(floatx4 (&acc)[4][4], const char* H,
                                      const unsigned short* WT,
                                      int wv, int lm, int q, int ln16) {
  const char* a0 = (const char*)WT + wv * 32768 + ln16;
  const int l7 = lm & 7;
  short8 af[4];
#pragma unroll
  for (int i = 0; i < 4; ++i) af[i] = *(const short8*)(a0 + ((i * 8) << 10));
#pragma unroll
  for (int kk = 0; kk < 8; ++kk) {
    short8 afn[4];
    if (kk < 7) {
#pragma unroll
      for (int i = 0; i < 4; ++i)
        afn[i] = *(const short8*)(a0 + ((i * 8 + kk + 1) << 10));
    }
    short8 bfr[4];
#pragma unroll
    for (int j = 0; j < 4; ++j) {
      const int pp = j * 16 + lm;
      const int c = kk * 4 + q;
      bfr[j] = *(const short8*)(H + pp * 512 + ((c ^ l7) << 4));
    }
#pragma unroll
    for (int i = 0; i < 4; ++i)
#pragma unroll
      for (int j = 0; j < 4; ++j)
        acc[i][j] = __builtin_amdgcn_mfma_f32_16x16x32_bf16(af[i], bfr[j], acc[i][j], 0, 0, 0);
    if (kk < 7) {
#pragma unroll
      for (int i = 0; i < 4; ++i) af[i] = afn[i];
    }
  }
}

__device__ __forceinline__ void epilogue(floatx4 (&acc)[4][4],
                                         const float* __restrict__ bias,
                                         char* Hout, int wv, int lm, int q) {
  const int l7 = lm & 7;
#pragma unroll
  for (int i = 0; i < 4; ++i) {
    const float4 bv = *(const float4*)(bias + wv * 64 + i * 16 + q * 4);
#pragma unroll
    for (int j = 0; j < 4; ++j) {
      unsigned int lo = (unsigned int)f2bf(__sinf(30.0f * (acc[i][j][0] + bv.x)))
                      | ((unsigned int)f2bf(__sinf(30.0f * (acc[i][j][1] + bv.y))) << 16);
      unsigned int hi = (unsigned int)f2bf(__sinf(30.0f * (acc[i][j][2] + bv.z)))
                      | ((unsigned int)f2bf(__sinf(30.0f * (acc[i][j][3] + bv.w))) << 16);
      const int pp = j * 16 + lm;
      const int c = wv * 8 + i * 2 + (q >> 1);
      uint2* dst = (uint2*)(Hout + pp * 512 + ((c ^ l7) << 4) + (q & 1) * 8);
      uint2 v; v.x = lo; v.y = hi;
      *dst = v;
    }
  }
}

__global__ __launch_bounds__(256, 4) void k_fused(
    const unsigned short* __restrict__ X0,
    const unsigned short* __restrict__ wp0, const float* __restrict__ b0p,
    const unsigned short* __restrict__ wp1, const float* __restrict__ b1,
    const unsigned short* __restrict__ wp2, const float* __restrict__ b2,
    const unsigned short* __restrict__ wp3, const float* __restrict__ b3,
    const unsigned short* __restrict__ wp4, const float* __restrict__ b4p,
    float* __restrict__ pat) {
  __shared__ alignas(128) char H[32768];
  const int tid = threadIdx.x;
  const int bid = blockIdx.x;
  const int pbase = bid * 64;
  const int bimg = pbase >> 16;
  const int y = (pbase >> 8) & 255;
  const int x0 = pbase & 255;  // 0,64,128,192
  const int lm = tid & 15;
  const int q = (tid & 63) >> 4;
  const int wv = tid >> 6;
  const int l7 = lm & 7;
  const int ln16 = (tid & 63) * 16;

  // ---- stage 3x66 pixel patch (1584 chunks of 16B, swizzled by row&7) ----
#pragma unroll
  for (int iter = 0; iter < 7; ++iter) {
    const int ci = iter * 256 + tid;
    if (ci < 1584) {
      const int rp = ci >> 3;
      const int row = rp / 66;
      const int col = rp - row * 66;
      int gy = y + row - 1;
      int gx = x0 + col - 1;
      gy = gy < 0 ? 0 : (gy > 255 ? 255 : gy);
      gx = gx < 0 ? 0 : (gx > 255 ? 255 : gx);
      const int gch = (ci & 7) ^ (rp & 7);
      const int p = (bimg << 16) + (gy << 8) + gx;
      gld16((const char*)X0 + (int64_t)p * 128 + gch * 16, H + ci * 16);
    }
  }
  __syncthreads();
  // zero out-of-range pixels (image edges)
#pragma unroll
  for (int iter = 0; iter < 7; ++iter) {
    const int ci = iter * 256 + tid;
    if (ci < 1584) {
      const int rp = ci >> 3;
      const int row = rp / 66;
      const int col = rp - row * 66;
      const int gy = y + row - 1;
      const int gx = x0 + col - 1;
      if ((unsigned)gy >= 256u || (unsigned)gx >= 256u) {
        uint4 z; z.x = 0; z.y = 0; z.z = 0; z.w = 0;
        *(uint4*)(H + ci * 16) = z;
      }
    }
  }
  __syncthreads();

  floatx4 zero = {0.0f, 0.0f, 0.0f, 0.0f};
  floatx4 acc[4][4];
#pragma unroll
  for (int i = 0; i < 4; ++i)
#pragma unroll
    for (int j = 0; j < 4; ++j) acc[i][j] = zero;

  // ---- layer 0: implicit 3x3 conv, 18 (tap,kk) steps, af pipelined ----
  {
    const char* a0 = (const char*)wp0 + wv * 73728 + ln16;
    short8 af[4];
#pragma unroll
    for (int i = 0; i < 4; ++i) af[i] = *(const short8*)(a0 + ((i * 18) << 10));
#pragma unroll
    for (int t = 0; t < 18; ++t) {
      const int tap = t >> 1;
      const int kk = t & 1;
      short8 afn[4];
      if (t < 17) {
#pragma unroll
        for (int i = 0; i < 4; ++i)
          afn[i] = *(const short8*)(a0 + ((i * 18 + t + 1) << 10));
      }
      const int dyr = tap / 3;
      const int dxr = tap - dyr * 3;
      const int rpb = dyr * 66 + dxr;
      short8 bfr[4];
#pragma unroll
      for (int j = 0; j < 4; ++j) {
        const int rp = rpb + j * 16 + lm;
        const int c = kk * 4 + q;
        bfr[j] = *(const short8*)(H + rp * 128 + ((c ^ (rp & 7)) << 4));
      }
#pragma unroll
      for (int i = 0; i < 4; ++i)
#pragma unroll
        for (int j = 0; j < 4; ++j)
          acc[i][j] = __builtin_amdgcn_mfma_f32_16x16x32_bf16(af[i], bfr[j], acc[i][j], 0, 0, 0);
      if (t < 17) {
#pragma unroll
        for (int i = 0; i < 4; ++i) af[i] = afn[i];
      }
    }
  }
  __syncthreads();             // all waves done reading patch
  epilogue(acc, b0p, H, wv, lm, q);
  __syncthreads();

  // ---- layers 1..3: in-place H ----
  const unsigned short* WTs[3] = {wp1, wp2, wp3};
  const float* Bs[3] = {b1, b2, b3};
#pragma unroll 1
  for (int l = 0; l < 3; ++l) {
#pragma unroll
    for (int i = 0; i < 4; ++i)
#pragma unroll
      for (int j = 0; j < 4; ++j) acc[i][j] = zero;
    mid_K(acc, H, WTs[l], wv, lm, q, ln16);
    __syncthreads();           // all reads of H done
    epilogue(acc, Bs[l], H, wv, lm, q);
    __syncthreads();
  }

  // ---- layer 4: H -> pat (each wave: 16-px strip x 32 features) ----
  {
    floatx4 a4[2];
    a4[0] = zero; a4[1] = zero;
    const char* aw = (const char*)wp4 + ln16;
    const int pp4 = wv * 16 + lm;
#pragma unroll
    for (int kk = 0; kk < 8; ++kk) {
      const int c = kk * 4 + q;
      short8 bfr = *(const short8*)(H + pp4 * 512 + ((c ^ l7) << 4));
#pragma unroll
      for (int i = 0; i < 2; ++i) {
        short8 af = *(const short8*)(aw + ((i * 8 + kk) << 10));
        a4[i] = __builtin_amdgcn_mfma_f32_16x16x32_bf16(af, bfr, a4[i], 0, 0, 0);
      }
    }
    float* outp = pat + (int64_t)(pbase + pp4) * 32;
#pragma unroll
    for (int i = 0; i < 2; ++i) {
      const float4 bb = *(const float4*)(b4p + i * 16 + q * 4);
      float4 v;
      v.x = a4[i][0] + bb.x;
      v.y = a4[i][1] + bb.y;
      v.z = a4[i][2] + bb.z;
      v.w = a4[i][3] + bb.w;
      *(float4*)(outp + i * 16 + q * 4) = v;  // cols 27..31 are padding
    }
  }
}

// fold3: out[b][c][y][x] = sum_{i,j} pat[(b,y+1-i,x+1-j)][c*9+i*3+j]
__global__ __launch_bounds__(256) void k_fold(const float* __restrict__ pat,
                                              float* __restrict__ out) {
  const int e = blockIdx.x * 256 + threadIdx.x;  // < 393216
  const int x = e & 255;
  const int y = (e >> 8) & 255;
  const int bc = e >> 16;
  const int c = bc % 3;
  const int b = bc / 3;
  float s = 0.0f;
#pragma unroll
  for (int i = 0; i < 3; ++i) {
    const int yy = y + 1 - i;
    if (yy < 0 || yy > 255) continue;
#pragma unroll
    for (int j = 0; j < 3; ++j) {
      const int xx = x + 1 - j;
      if (xx < 0 || xx > 255) continue;
      s += pat[(int64_t)((b << 16) + yy * 256 + xx) * 32 + c * 9 + i * 3 + j];
    }
  }
  out[e] = s;
}

extern "C" void kernel_launch(void* const* d_in, const int* in_sizes, int n_in,
                              void* d_out, int out_size, void* d_ws, size_t ws_size,
                              hipStream_t stream) {
  const float* feat  = (const float*)d_in[0];
  const float* coord = (const float*)d_in[1];
  const float* w0 = (const float*)d_in[2];
  const float* b0 = (const float*)d_in[3];
  const float* w1 = (const float*)d_in[4];
  const float* b1 = (const float*)d_in[5];
  const float* w2 = (const float*)d_in[6];
  const float* b2 = (const float*)d_in[7];
  const float* w3 = (const float*)d_in[8];
  const float* b3 = (const float*)d_in[9];
  const float* w4 = (const float*)d_in[10];
  const float* b4 = (const float*)d_in[11];

  char* ws = (char*)d_ws;
  unsigned short* X0  = (unsigned short*)(ws);                 // 16.78 MB
  float*          pat = (float*)(ws + 16777216);               // 16.78 MB
  unsigned short* wp0 = (unsigned short*)(ws + 33554432);      // 294912 B
  unsigned short* wp1 = (unsigned short*)(ws + 33849344);      // 131072 B
  unsigned short* wp2 = (unsigned short*)(ws + 33980416);
  unsigned short* wp3 = (unsigned short*)(ws + 34111488);
  unsigned short* wp4 = (unsigned short*)(ws + 34242560);      // 16384 B
  float*          b0p = (float*)(ws + 34258944);               // 1024 B
  float*          b4p = (float*)(ws + 34259968);               // 128 B
  float* out = (float*)d_out;

  hipLaunchKernelGGL(k_pre, dim3(1890), dim3(256), 0, stream,
                     feat, w0, b0, w1, w2, w3, w4, b4, coord,
                     X0, wp0, wp1, wp2, wp3, wp4, b0p, b4p);
  hipLaunchKernelGGL(k_fused, dim3(2048), dim3(256), 0, stream,
                     X0, wp0, b0p, wp1, b1, wp2, b2, wp3, b3, wp4, b4p, pat);
  hipLaunchKernelGGL(k_fold, dim3(1536), dim3(256), 0, stream, pat, out);
}

// Round 5
// 193.380 us; speedup vs baseline: 1.5745x; 1.2841x over previous
//
#include <hip/hip_runtime.h>
#include <stdint.h>

typedef __attribute__((ext_vector_type(8))) short short8;
typedef __attribute__((ext_vector_type(4))) float floatx4;

#define AS1 __attribute__((address_space(1)))
#define AS3 __attribute__((address_space(3)))

__device__ __forceinline__ void gld16(const void* g, void* l) {
  __builtin_amdgcn_global_load_lds((AS1 const void*)g, (AS3 void*)l, 16, 0, 0);
}

__device__ __forceinline__ unsigned short f2bf(float f) {
  unsigned int u = __float_as_uint(f);
  return (unsigned short)((u + 0x7fffu + ((u >> 16) & 1u)) >> 16);
}

// ---------------------------------------------------------------------------
// k_pre: blocks [0,512) = featT (X0[p][c] = bf16 feat, pixel-major 128B rows);
// blocks [512,...) = weight packing into MFMA A-fragment order.
// Packed: per (panel of 16 out-features, step) one 1KB chunk, element (lane,j)
// at chunk + lane*16 + j*2 -> feature = panel*16 + (lane&15),
// k = kk*32 + (lane>>4)*8 + j.  Every af load = coalesced 1KB burst.
// wp0: 16 panels x 18 steps(tap*2+kk);  wp{1,2,3}: 16 panels x 8 kk;
// wp4: 2 panels x 8 kk (feature>=27 -> 0).
// b0p[n] = b0[n] + t*w0[576*256+n];  b4p = b4 padded to 32.
// ---------------------------------------------------------------------------
__global__ __launch_bounds__(256) void k_pre(
    const float* __restrict__ feat,
    const float* __restrict__ w0, const float* __restrict__ b0,
    const float* __restrict__ w1, const float* __restrict__ w2,
    const float* __restrict__ w3, const float* __restrict__ w4,
    const float* __restrict__ b4, const float* __restrict__ coord,
    unsigned short* __restrict__ X0,
    unsigned short* __restrict__ wp0, unsigned short* __restrict__ wp1,
    unsigned short* __restrict__ wp2, unsigned short* __restrict__ wp3,
    unsigned short* __restrict__ wp4, float* __restrict__ b0p,
    float* __restrict__ b4p) {
  const int bid = blockIdx.x;
  const int tid = threadIdx.x;
  if (bid < 512) {
    const int p = bid * 256 + tid;
    const int b = p >> 16;
    const int off = p & 65535;
    const float* src = feat + ((int64_t)b << 22) + off;
    unsigned int tw[32];
#pragma unroll
    for (int c = 0; c < 32; ++c) {
      float lo = src[(int64_t)(2 * c) << 16];
      float hi = src[(int64_t)(2 * c + 1) << 16];
      tw[c] = (unsigned int)f2bf(lo) | ((unsigned int)f2bf(hi) << 16);
    }
    uint4* dst = (uint4*)(X0 + (int64_t)p * 64);
#pragma unroll
    for (int k = 0; k < 8; ++k) {
      uint4 v;
      v.x = tw[4 * k]; v.y = tw[4 * k + 1]; v.z = tw[4 * k + 2]; v.w = tw[4 * k + 3];
      dst[k] = v;
    }
    return;
  }
  const int e = (bid - 512) * 256 + tid;
  if (e < 147456) {
    const int j = e & 7, lane = (e >> 3) & 63, r = e >> 9;
    const int kk = r & 1, s = r >> 1;
    const int tap = s % 9, panel = s / 9;
    const int feature = panel * 16 + (lane & 15);
    const int c = kk * 32 + (lane >> 4) * 8 + j;
    wp0[e] = f2bf(w0[(c * 9 + tap) * 256 + feature]);
  } else if (e < 344064) {
    const int e2 = e - 147456;
    const int l = e2 >> 16;
    const int u = e2 & 65535;
    const int j = u & 7, lane = (u >> 3) & 63, kk = (u >> 9) & 7, panel = (u >> 12) & 15;
    const int feature = panel * 16 + (lane & 15);
    const int k = kk * 32 + (lane >> 4) * 8 + j;
    const float* w = (l == 0) ? w1 : (l == 1) ? w2 : w3;
    unsigned short* wt = (l == 0) ? wp1 : (l == 1) ? wp2 : wp3;
    wt[u] = f2bf(w[k * 256 + feature]);
  } else if (e < 352256) {
    const int u = e - 344064;
    const int j = u & 7, lane = (u >> 3) & 63, kk = (u >> 9) & 7, i = (u >> 12) & 1;
    const int feature = i * 16 + (lane & 15);
    const int k = kk * 32 + (lane >> 4) * 8 + j;
    wp4[u] = (feature < 27) ? f2bf(w4[k * 27 + feature]) : (unsigned short)0;
  } else if (e < 352512) {
    const int n = e - 352256;
    b0p[n] = b0[n] + coord[2] * w0[576 * 256 + n];
  } else if (e < 352544) {
    const int n = e - 352512;
    b4p[n] = (n < 27) ? b4[n] : 0.0f;
  }
}

// ---------------------------------------------------------------------------
// Fused MLP. Block = 128 pixels (half image row), 4 waves, H = 64KB in-place.
// A = packed weights (1KB coalesced bursts, L2-hot, 1-step prefetch),
// B = activations (LDS).  mid_K reads ALL of H; barrier; epilogue writes H
// in place.  Bias pre-loaded into accumulators.
// H layout: px-major 512B/px, chunk c at px*512 + ((c^(px&7))<<4).
// Layer-0 patch: 3 rows x 130 px x 128B = 48.75KB aliases H.
// pat is plane-major: pat[g*131072 + p], g=0..26.
// ---------------------------------------------------------------------------
__device__ __forceinline__ void acc_init(floatx4 (&acc)[4][8],
                                         const float* __restrict__ bias,
                                         int wv, int lm, int q) {
#pragma unroll
  for (int i = 0; i < 4; ++i) {
    const float4 bv = *(const float4*)(bias + wv * 64 + i * 16 + q * 4);
    floatx4 a;
    a[0] = bv.x; a[1] = bv.y; a[2] = bv.z; a[3] = bv.w;
#pragma unroll
    for (int j = 0; j < 8; ++j) acc[i][j] = a;
  }
}

__device__ __forceinline__ void mid_K(floatx4 (&acc)[4][8], const char* H,
                                      const unsigned short* WT,
                                      int wv, int lm, int q, int ln16) {
  const char* a0 = (const char*)WT + wv * 32768 + ln16;
  const int l7 = lm & 7;
  short8 af[4];
#pragma unroll
  for (int i = 0; i < 4; ++i) af[i] = *(const short8*)(a0 + ((i * 8) << 10));
#pragma unroll
  for (int kk = 0; kk < 8; ++kk) {
    short8 afn[4];
    if (kk < 7) {
#pragma unroll
      for (int i = 0; i < 4; ++i)
        afn[i] = *(const short8*)(a0 + ((i * 8 + kk + 1) << 10));
    }
#pragma unroll
    for (int j = 0; j < 8; ++j) {
      const int pp = j * 16 + lm;
      const int c = kk * 4 + q;
      const short8 bfr = *(const short8*)(H + pp * 512 + ((c ^ l7) << 4));
#pragma unroll
      for (int i = 0; i < 4; ++i)
        acc[i][j] = __builtin_amdgcn_mfma_f32_16x16x32_bf16(af[i], bfr, acc[i][j], 0, 0, 0);
    }
    if (kk < 7) {
#pragma unroll
      for (int i = 0; i < 4; ++i) af[i] = afn[i];
    }
  }
}

__device__ __forceinline__ void epilogue(floatx4 (&acc)[4][8], char* Hout,
                                         int wv, int lm, int q) {
  const int l7 = lm & 7;
#pragma unroll
  for (int i = 0; i < 4; ++i) {
#pragma unroll
    for (int j = 0; j < 8; ++j) {
      unsigned int lo = (unsigned int)f2bf(__sinf(30.0f * acc[i][j][0]))
                      | ((unsigned int)f2bf(__sinf(30.0f * acc[i][j][1])) << 16);
      unsigned int hi = (unsigned int)f2bf(__sinf(30.0f * acc[i][j][2]))
                      | ((unsigned int)f2bf(__sinf(30.0f * acc[i][j][3])) << 16);
      const int pp = j * 16 + lm;
      const int c = wv * 8 + i * 2 + (q >> 1);
      uint2 v; v.x = lo; v.y = hi;
      *(uint2*)(Hout + pp * 512 + ((c ^ l7) << 4) + (q & 1) * 8) = v;
    }
  }
}

__global__ __launch_bounds__(256, 2) void k_fused(
    const unsigned short* __restrict__ X0,
    const unsigned short* __restrict__ wp0, const float* __restrict__ b0p,
    const unsigned short* __restrict__ wp1, const float* __restrict__ b1,
    const unsigned short* __restrict__ wp2, const float* __restrict__ b2,
    const unsigned short* __restrict__ wp3, const float* __restrict__ b3,
    const unsigned short* __restrict__ wp4, const float* __restrict__ b4p,
    float* __restrict__ pat) {
  __shared__ alignas(128) char H[65536];
  const int tid = threadIdx.x;
  const int bid = blockIdx.x;
  const int pbase = bid * 128;
  const int bimg = pbase >> 16;
  const int y = (pbase >> 8) & 255;
  const int x0 = pbase & 255;  // 0 or 128
  const int lm = tid & 15;
  const int q = (tid & 63) >> 4;
  const int wv = tid >> 6;
  const int l7 = lm & 7;
  const int ln16 = (tid & 63) * 16;

  // ---- stage 3x130 pixel patch (3120 chunks of 16B, swizzled by rp&7) ----
#pragma unroll
  for (int iter = 0; iter < 13; ++iter) {
    const int ci = iter * 256 + tid;
    if (ci < 3120) {
      const int rp = ci >> 3;
      const int row = rp / 130;
      const int col = rp - row * 130;
      int gy = y + row - 1;
      int gx = x0 + col - 1;
      gy = gy < 0 ? 0 : (gy > 255 ? 255 : gy);
      gx = gx < 0 ? 0 : (gx > 255 ? 255 : gx);
      const int gch = (ci & 7) ^ (rp & 7);
      const int p = (bimg << 16) + (gy << 8) + gx;
      gld16((const char*)X0 + (int64_t)p * 128 + gch * 16, H + ci * 16);
    }
  }
  __syncthreads();
  // zero out-of-range pixels (image edges)
#pragma unroll
  for (int iter = 0; iter < 13; ++iter) {
    const int ci = iter * 256 + tid;
    if (ci < 3120) {
      const int rp = ci >> 3;
      const int row = rp / 130;
      const int col = rp - row * 130;
      const int gy = y + row - 1;
      const int gx = x0 + col - 1;
      if ((unsigned)gy >= 256u || (unsigned)gx >= 256u) {
        uint4 z; z.x = 0; z.y = 0; z.z = 0; z.w = 0;
        *(uint4*)(H + ci * 16) = z;
      }
    }
  }
  __syncthreads();

  floatx4 acc[4][8];
  acc_init(acc, b0p, wv, lm, q);

  // ---- layer 0: implicit 3x3 conv, 18 (tap,kk) steps, af pipelined ----
  {
    const char* a0 = (const char*)wp0 + wv * 73728 + ln16;
    short8 af[4];
#pragma unroll
    for (int i = 0; i < 4; ++i) af[i] = *(const short8*)(a0 + ((i * 18) << 10));
#pragma unroll
    for (int t = 0; t < 18; ++t) {
      const int tap = t >> 1;
      const int kk = t & 1;
      short8 afn[4];
      if (t < 17) {
#pragma unroll
        for (int i = 0; i < 4; ++i)
          afn[i] = *(const short8*)(a0 + ((i * 18 + t + 1) << 10));
      }
      const int dyr = tap / 3;
      const int dxr = tap - dyr * 3;
      const int rpb = dyr * 130 + dxr;
#pragma unroll
      for (int j = 0; j < 8; ++j) {
        const int rp = rpb + j * 16 + lm;
        const int c = kk * 4 + q;
        const short8 bfr = *(const short8*)(H + rp * 128 + ((c ^ (rp & 7)) << 4));
#pragma unroll
        for (int i = 0; i < 4; ++i)
          acc[i][j] = __builtin_amdgcn_mfma_f32_16x16x32_bf16(af[i], bfr, acc[i][j], 0, 0, 0);
      }
      if (t < 17) {
#pragma unroll
        for (int i = 0; i < 4; ++i) af[i] = afn[i];
      }
    }
  }
  __syncthreads();             // all waves done reading patch
  epilogue(acc, H, wv, lm, q);
  __syncthreads();

  // ---- layers 1..3: in-place H ----
  const unsigned short* WTs[3] = {wp1, wp2, wp3};
  const float* Bs[3] = {b1, b2, b3};
#pragma unroll 1
  for (int l = 0; l < 3; ++l) {
    acc_init(acc, Bs[l], wv, lm, q);
    mid_K(acc, H, WTs[l], wv, lm, q, ln16);
    __syncthreads();           // all reads of H done
    epilogue(acc, H, wv, lm, q);
    __syncthreads();
  }

  // ---- layer 4: H -> pat planes (each wave: 32-px strip x 32 features) ----
  {
    floatx4 a4[2][2];
#pragma unroll
    for (int i = 0; i < 2; ++i) {
      const float4 bb = *(const float4*)(b4p + i * 16 + q * 4);
      floatx4 a;
      a[0] = bb.x; a[1] = bb.y; a[2] = bb.z; a[3] = bb.w;
      a4[i][0] = a; a4[i][1] = a;
    }
    const char* aw = (const char*)wp4 + ln16;
#pragma unroll
    for (int kk = 0; kk < 8; ++kk) {
      const short8 af0 = *(const short8*)(aw + (kk << 10));
      const short8 af1 = *(const short8*)(aw + ((8 + kk) << 10));
#pragma unroll
      for (int jj = 0; jj < 2; ++jj) {
        const int pp = wv * 32 + jj * 16 + lm;
        const int c = kk * 4 + q;
        const short8 bfr = *(const short8*)(H + pp * 512 + ((c ^ l7) << 4));
        a4[0][jj] = __builtin_amdgcn_mfma_f32_16x16x32_bf16(af0, bfr, a4[0][jj], 0, 0, 0);
        a4[1][jj] = __builtin_amdgcn_mfma_f32_16x16x32_bf16(af1, bfr, a4[1][jj], 0, 0, 0);
      }
    }
#pragma unroll
    for (int i = 0; i < 2; ++i)
#pragma unroll
      for (int jj = 0; jj < 2; ++jj)
#pragma unroll
        for (int r = 0; r < 4; ++r) {
          const int g = i * 16 + q * 4 + r;
          if (g < 27)
            pat[g * 131072 + pbase + wv * 32 + jj * 16 + lm] = a4[i][jj][r];
        }
  }
}

// fold3 (plane-major pat): out[b][c][y][x] =
//   sum_{i,j} pat[(c*9+i*3+j)*131072 + b*65536 + (y+1-i)*256 + (x+1-j)]
__global__ __launch_bounds__(256) void k_fold(const float* __restrict__ pat,
                                              float* __restrict__ out) {
  const int e = blockIdx.x * 256 + threadIdx.x;  // < 393216
  const int x = e & 255;
  const int y = (e >> 8) & 255;
  const int bc = e >> 16;
  const int c = bc % 3;
  const int b = bc / 3;
  float s = 0.0f;
#pragma unroll
  for (int i = 0; i < 3; ++i) {
    const int yy = y + 1 - i;
    if (yy < 0 || yy > 255) continue;
#pragma unroll
    for (int j = 0; j < 3; ++j) {
      const int xx = x + 1 - j;
      if (xx < 0 || xx > 255) continue;
      s += pat[(c * 9 + i * 3 + j) * 131072 + (b << 16) + yy * 256 + xx];
    }
  }
  out[e] = s;
}

extern "C" void kernel_launch(void* const* d_in, const int* in_sizes, int n_in,
                              void* d_out, int out_size, void* d_ws, size_t ws_size,
                              hipStream_t stream) {
  const float* feat  = (const float*)d_in[0];
  const float* coord = (const float*)d_in[1];
  const float* w0 = (const float*)d_in[2];
  const float* b0 = (const float*)d_in[3];
  const float* w1 = (const float*)d_in[4];
  const float* b1 = (const float*)d_in[5];
  const float* w2 = (const float*)d_in[6];
  const float* b2 = (const float*)d_in[7];
  const float* w3 = (const float*)d_in[8];
  const float* b3 = (const float*)d_in[9];
  const float* w4 = (const float*)d_in[10];
  const float* b4 = (const float*)d_in[11];

  char* ws = (char*)d_ws;
  unsigned short* X0  = (unsigned short*)(ws);                 // 16.78 MB
  float*          pat = (float*)(ws + 16777216);               // 14.16 MB (27 planes)
  unsigned short* wp0 = (unsigned short*)(ws + 33554432);      // 294912 B
  unsigned short* wp1 = (unsigned short*)(ws + 33849344);      // 131072 B
  unsigned short* wp2 = (unsigned short*)(ws + 33980416);
  unsigned short* wp3 = (unsigned short*)(ws + 34111488);
  unsigned short* wp4 = (unsigned short*)(ws + 34242560);      // 16384 B
  float*          b0p = (float*)(ws + 34258944);               // 1024 B
  float*          b4p = (float*)(ws + 34259968);               // 128 B
  float* out = (float*)d_out;

  hipLaunchKernelGGL(k_pre, dim3(1890), dim3(256), 0, stream,
                     feat, w0, b0, w1, w2, w3, w4, b4, coord,
                     X0, wp0, wp1, wp2, wp3, wp4, b0p, b4p);
  hipLaunchKernelGGL(k_fused, dim3(1024), dim3(256), 0, stream,
                     X0, wp0, b0p, wp1, b1, wp2, b2, wp3, b3, wp4, b4p, pat);
  hipLaunchKernelGGL(k_fold, dim3(1536), dim3(256), 0, stream, pat, out);
}